// Round 10
// baseline (207.567 us; speedup 1.0000x reference)
//
#include <hip/hip_runtime.h>

typedef unsigned short u16;
typedef unsigned int u32;
typedef __attribute__((ext_vector_type(8))) short short8;
typedef __attribute__((ext_vector_type(4))) float float4v;

struct alignas(8) U16x4 { u16 x, y, z, w; };

// fp32 -> bf16 round-to-nearest-even
__device__ __forceinline__ u16 f2b(float f) {
    union { float f; unsigned int u; } v; v.f = f;
    unsigned int r = (v.u >> 16) & 1u;
    v.u += 0x7fffu + r;
    return (u16)(v.u >> 16);
}

__device__ __forceinline__ float b2f_lo(u32 u) {
    union { unsigned int u; float f; } v; v.u = u << 16; return v.f;
}
__device__ __forceinline__ float b2f_hi(u32 u) {
    union { unsigned int u; float f; } v; v.u = u & 0xffff0000u; return v.f;
}

// async global->LDS, 16B per lane; LDS dest = wave-uniform base + lane*16
__device__ __forceinline__ void gld16(const u16* g, u16* l) {
    __builtin_amdgcn_global_load_lds(
        (const __attribute__((address_space(1))) void*)g,
        (__attribute__((address_space(3))) void*)l, 16, 0, 0);
}

// read a short8 fragment from an XOR-swizzled [rows][64] u16 LDS tile.
// chunk cg (16B units within the 128B row) is stored at slot cg^(row&7).
__device__ __forceinline__ short8 frag8(const u16* base, int row, int cg) {
    return *(const short8*)(base + row * 64 + ((cg ^ (row & 7)) << 3));
}

// ---------------------------------------------------------------------------
// prep (merged): id<4096 -> x fp32->bf16 (1024 el/block);
// id>=4096 -> 32x32 transpose+cvt tile of W[z]
// ---------------------------------------------------------------------------
__global__ __launch_bounds__(256) void prep_kernel(
    const float* __restrict__ x, const float* __restrict__ W0,
    const float* __restrict__ W1, const float* __restrict__ W2,
    const float* __restrict__ W3, u16* __restrict__ xb,
    u16* __restrict__ T0, u16* __restrict__ T1,
    u16* __restrict__ T2, u16* __restrict__ T3) {
    __shared__ float tile[32][33];
    int id = blockIdx.x;
    if (id < 4096) {
        size_t i = ((size_t)id * 256 + threadIdx.x) * 4;
        float4 v = *(const float4*)(x + i);
        U16x4 o;
        o.x = f2b(v.x); o.y = f2b(v.y); o.z = f2b(v.z); o.w = f2b(v.w);
        *(U16x4*)(xb + i) = o;
        return;
    }
    int r = id - 4096;
    int z = r >> 10, tl = r & 1023;
    const float* W = (z == 0) ? W0 : (z == 1) ? W1 : (z == 2) ? W2 : W3;
    u16* T = (z == 0) ? T0 : (z == 1) ? T1 : (z == 2) ? T2 : T3;
    int t = threadIdx.x;
    int tx = t & 31, ty = t >> 5;
    int bn = (tl & 31) * 32, bk = (tl >> 5) * 32;
#pragma unroll
    for (int p = 0; p < 4; ++p) {
        int k = ty + p * 8;
        tile[k][tx] = W[(size_t)(bk + k) * 1024 + bn + tx];
    }
    __syncthreads();
#pragma unroll
    for (int p = 0; p < 4; ++p) {
        int n = ty + p * 8;
        T[(size_t)(bn + n) * 1024 + bk + tx] = f2b(tile[tx][n]);
    }
}

// ---------------------------------------------------------------------------
// GEMM core (m97 structure), 256 thr / 4 waves 2x2, 64x64 per wave.
// ---------------------------------------------------------------------------
__device__ __forceinline__ void gemm_core_gld(const u16* __restrict__ A,
                                              const u16* __restrict__ BT,
                                              int m0, int n0, int t,
                                              u16* As, u16* Bs,
                                              float4v acc[4][4]) {
    int lane = t & 63, wid = t >> 6;
    int wr = wid >> 1, wc = wid & 1;
    int l16 = lane & 15, quad = lane >> 4;
    int rl = lane >> 3, cs = lane & 7;   // staging: row-within-instr, stored slot

    for (int k0 = 0; k0 < 1024; k0 += 64) {
        __syncthreads();
#pragma unroll
        for (int p = 0; p < 4; ++p) {
            int blk = wid * 4 + p;           // 0..15
            int row = blk * 8 + rl;          // 0..127
            int c = cs ^ (row & 7);          // global 16B-chunk to fetch
            gld16(A + (size_t)(m0 + row) * 1024 + k0 + c * 8, As + blk * 512);
            gld16(BT + (size_t)(n0 + row) * 1024 + k0 + c * 8, Bs + blk * 512);
        }
        __syncthreads();   // vmcnt(0) drained here -> LDS tiles ready
#pragma unroll
        for (int ks = 0; ks < 64; ks += 32) {
            int cg = (ks >> 3) + quad;
            short8 af[4], bf[4];
#pragma unroll
            for (int i = 0; i < 4; ++i) af[i] = frag8(As, wr * 64 + i * 16 + l16, cg);
#pragma unroll
            for (int j = 0; j < 4; ++j) bf[j] = frag8(Bs, wc * 64 + j * 16 + l16, cg);
#pragma unroll
            for (int i = 0; i < 4; ++i)
#pragma unroll
                for (int j = 0; j < 4; ++j)
                    acc[i][j] = __builtin_amdgcn_mfma_f32_16x16x32_bf16(
                        af[i], bf[j], acc[i][j], 0, 0, 0);
        }
    }
}

// ---------------------------------------------------------------------------
// Fused QKV projection. grid = 768 flat, XCD-swizzled (id%8 == m%8).
// z=0: Q bf16 pre-scaled by 0.125*log2(e); z=1: K bf16; z=2: V^T [B,H,dk,S].
// ---------------------------------------------------------------------------
__global__ __launch_bounds__(256) void qkv_kernel(
    const u16* __restrict__ X,
    const u16* __restrict__ WqT, const u16* __restrict__ WkT, const u16* __restrict__ WvT,
    const float* __restrict__ bq, const float* __restrict__ bk, const float* __restrict__ bv,
    u16* __restrict__ Qo, u16* __restrict__ Ko, u16* __restrict__ VTo) {
    __shared__ __align__(16) u16 As[128 * 64];
    __shared__ __align__(16) u16 Bs[128 * 64];
    int id = blockIdx.x;                       // 768 = 8 xcd * 4 mgrp * 24 nz
    int m = (id & 7) | (((id >> 3) & 3) << 3); // id%8 == m%8 -> same XCD per m
    int nz = id >> 5;                          // 0..23
    int n = nz & 7, z = nz >> 3;
    const u16* BT = (z == 0) ? WqT : (z == 1) ? WkT : WvT;
    const float* bias = (z == 0) ? bq : (z == 1) ? bk : bv;
    int t = threadIdx.x;
    int m0 = m * 128, n0 = n * 128;

    float4v acc[4][4];
    float4v zero4 = {0.f, 0.f, 0.f, 0.f};
#pragma unroll
    for (int i = 0; i < 4; ++i)
#pragma unroll
        for (int j = 0; j < 4; ++j) acc[i][j] = zero4;

    gemm_core_gld(X, BT, m0, n0, t, As, Bs, acc);

    int lane = t & 63, wid = t >> 6;
    int wr = wid >> 1, wc = wid & 1;
    int l16 = lane & 15, quad = lane >> 4;
    // 0.125 * log2(e): flash computes softmax via exp2
    float scale = (z == 0) ? 0.18033688011112042f : 1.0f;

#pragma unroll
    for (int j = 0; j < 4; ++j) {
        int n1 = n0 + wc * 64 + j * 16 + l16;
        float bvl = bias[n1];
#pragma unroll
        for (int i = 0; i < 4; ++i) {
            int mbase = m0 + wr * 64 + i * 16 + quad * 4;
            if (z < 2) {
                u16* out = (z == 0) ? Qo : Ko;
#pragma unroll
                for (int r = 0; r < 4; ++r)
                    out[(size_t)(mbase + r) * 1024 + n1] =
                        f2b((acc[i][j][r] + bvl) * scale);
            } else {
                // V^T [B,H,dk,S]: rows r are consecutive s -> 8B vector store
                int bidx = mbase >> 11, s = mbase & 2047;
                size_t base =
                    ((size_t)((bidx * 16 + (n1 >> 6)) * 64 + (n1 & 63))) * 2048 + s;
                U16x4 pk;
                pk.x = f2b(acc[i][j][0] + bvl);
                pk.y = f2b(acc[i][j][1] + bvl);
                pk.z = f2b(acc[i][j][2] + bvl);
                pk.w = f2b(acc[i][j][3] + bvl);
                *(U16x4*)(VTo + base) = pk;
            }
        }
    }
}

// ---------------------------------------------------------------------------
// Output projection WITH FUSED COMBINE. grid = 256 flat, XCD-swizzled
// (id%8 == m%8), 512 threads = 8 waves (2x4 grid, 64x32/wave).
// A-staging computes As = bf16((O0+O1) * 1/(l0+l1)) from the flash partials
// in-line (head = k0>>6 is wave-uniform since k0 is 64-aligned), replacing
// the old separate combine kernel; bit-identical to the combine->gld16 path.
// Bs (weights) stays gld16.
// ---------------------------------------------------------------------------
__global__ __launch_bounds__(512) void oproj_kernel(const u16* __restrict__ Op,
                                                    const float* __restrict__ lp,
                                                    const u16* __restrict__ WoT,
                                                    const float* __restrict__ bias,
                                                    float* __restrict__ out) {
    __shared__ __align__(16) u16 As[128 * 64];
    __shared__ __align__(16) u16 Bs[128 * 64];
    int id = blockIdx.x;                       // 256 = 8 xcd * 4 mgrp * 8 n
    int m = (id & 7) | (((id >> 3) & 3) << 3);
    int n = id >> 5;
    int t = threadIdx.x;
    int m0 = m * 128, n0 = n * 128;
    int lane = t & 63, wid = t >> 6;           // wid 0..7
    int wr = wid >> 2, wc = wid & 3;           // 2 x 4 wave grid; 64x32 / wave
    int l16 = lane & 15, quad = lane >> 4;
    int rl = lane >> 3, cs = lane & 7;

    float4v acc[4][2];
    float4v zero4 = {0.f, 0.f, 0.f, 0.f};
#pragma unroll
    for (int i = 0; i < 4; ++i)
#pragma unroll
        for (int j = 0; j < 2; ++j) acc[i][j] = zero4;

    for (int k0 = 0; k0 < 1024; k0 += 64) {
        int head = k0 >> 6;                  // wave-uniform head for this k-tile
        __syncthreads();
#pragma unroll
        for (int p = 0; p < 2; ++p) {
            int blk = wid * 2 + p;           // 0..15
            int row = blk * 8 + rl;          // 0..127
            int c = cs ^ (row & 7);
            // Bs: weights via async DMA
            gld16(WoT + (size_t)(n0 + row) * 1024 + k0 + c * 8, Bs + blk * 512);
            // As: fused combine of flash partials
            size_t off = (size_t)(m0 + row) * 1024 + k0 + c * 8;
            uint4 a0 = *(const uint4*)(Op + off);
            uint4 a1 = *(const uint4*)(Op + 4194304 + off);
            float l0 = lp[(m0 + row) * 16 + head];
            float l1 = lp[65536 + (m0 + row) * 16 + head];
            float inv = 1.0f / (l0 + l1);
            uint4 pk;
            u32 s0, s1;
            s0 = f2b(b2f_lo(a0.x) + b2f_lo(a1.x)) | ((u32)f2b((b2f_hi(a0.x) + b2f_hi(a1.x)) * inv) << 16);
            // note: low half also needs * inv — compute both explicitly:
            s0 = (u32)f2b((b2f_lo(a0.x) + b2f_lo(a1.x)) * inv) |
                 ((u32)f2b((b2f_hi(a0.x) + b2f_hi(a1.x)) * inv) << 16);
            s1 = (u32)f2b((b2f_lo(a0.y) + b2f_lo(a1.y)) * inv) |
                 ((u32)f2b((b2f_hi(a0.y) + b2f_hi(a1.y)) * inv) << 16);
            pk.x = s0; pk.y = s1;
            s0 = (u32)f2b((b2f_lo(a0.z) + b2f_lo(a1.z)) * inv) |
                 ((u32)f2b((b2f_hi(a0.z) + b2f_hi(a1.z)) * inv) << 16);
            s1 = (u32)f2b((b2f_lo(a0.w) + b2f_lo(a1.w)) * inv) |
                 ((u32)f2b((b2f_hi(a0.w) + b2f_hi(a1.w)) * inv) << 16);
            pk.z = s0; pk.w = s1;
            *(uint4*)(As + blk * 512 + lane * 8) = pk;
        }
        __syncthreads();
#pragma unroll
        for (int ks = 0; ks < 64; ks += 32) {
            int cg = (ks >> 3) + quad;
            short8 af[4], bf[2];
#pragma unroll
            for (int i = 0; i < 4; ++i) af[i] = frag8(As, wr * 64 + i * 16 + l16, cg);
#pragma unroll
            for (int j = 0; j < 2; ++j) bf[j] = frag8(Bs, wc * 32 + j * 16 + l16, cg);
#pragma unroll
            for (int i = 0; i < 4; ++i)
#pragma unroll
                for (int j = 0; j < 2; ++j)
                    acc[i][j] = __builtin_amdgcn_mfma_f32_16x16x32_bf16(
                        af[i], bf[j], acc[i][j], 0, 0, 0);
        }
    }

#pragma unroll
    for (int j = 0; j < 2; ++j) {
        int n1 = n0 + wc * 32 + j * 16 + l16;
        float bvl = bias[n1];
#pragma unroll
        for (int i = 0; i < 4; ++i) {
            int mbase = m0 + wr * 64 + i * 16 + quad * 4;
#pragma unroll
            for (int r = 0; r < 4; ++r)
                out[(size_t)(mbase + r) * 1024 + n1] = acc[i][j][r] + bvl;
        }
    }
}

// ---------------------------------------------------------------------------
// Flash attention v6 (R7, proven 51 us): 64 q/wave amortizes per-wave K/V
// fragment reads. grid = 1024 flat, XCD-swizzled (id%8 == bh%8): 8 xcd *
// 4 bhgrp * 16 qb * 2 kvz. 128 thr = 2 waves, q-tile 128 (64 q/wave),
// 64-key tiles, kv-split x2. Wave0 stages K, wave1 stages V (gld16).
// S^T = K*Q^T per 16-key C-tile, exp2 + b64 pack; PV + ones-MFMA denom.
// NOTE (R8 errata): VGPR register-prefetch of K/V spilled to scratch
// (WRITE_SIZE 20->135 MB, 2x slower). Do not re-introduce.
// ---------------------------------------------------------------------------
__global__ __launch_bounds__(128, 2) void flash_kernel(const u16* __restrict__ Q,
                                                       const u16* __restrict__ Kn,
                                                       const u16* __restrict__ VT,
                                                       u16* __restrict__ Opart,
                                                       float* __restrict__ lpart) {
    __shared__ __align__(16) u16 Ks[64 * 64];   // [key][dim] swizzled
    __shared__ __align__(16) u16 Vs[64 * 64];   // [dim][key] swizzled
    __shared__ __align__(16) u16 Ps[128][72];   // [q][key] padded (b64 w / b128 r)

    int id = blockIdx.x;                        // 1024
    int bh = (id & 7) | (((id >> 3) & 3) << 3); // id%8 == bh%8
    int rest = id >> 5;                         // 0..31
    int qb = rest & 15, kvz = rest >> 4;
    int b = bh >> 4, h = bh & 15;
    int t = threadIdx.x;
    int wid = t >> 6, lane = t & 63;
    int l16 = lane & 15, quad = lane >> 4;
    int rl = lane >> 3, cs = lane & 7;
    int q0 = qb * 128 + wid * 64;         // wave's first query
    size_t kbase = (size_t)(b * 2048) * 1024 + h * 64;
    size_t vbase = (size_t)(bh * 64) * 2048;

    // Q B-fragments (n=q, k=dim), direct from global (64B/row coalesced)
    short8 qf[4][2];
#pragma unroll
    for (int j = 0; j < 4; ++j)
#pragma unroll
        for (int kk = 0; kk < 2; ++kk)
            qf[j][kk] = *(const short8*)(
                Q + ((size_t)(b * 2048 + q0 + j * 16 + l16)) * 1024 + h * 64 +
                kk * 32 + quad * 8);

    float4v oacc[4][4], lacc[4];
    float4v zero4 = {0.f, 0.f, 0.f, 0.f};
#pragma unroll
    for (int ip = 0; ip < 4; ++ip) {
        lacc[ip] = zero4;
#pragma unroll
        for (int jd = 0; jd < 4; ++jd) oacc[ip][jd] = zero4;
    }

    const short ONE = (short)0x3F80;  // bf16 1.0
    short8 ones = {ONE, ONE, ONE, ONE, ONE, ONE, ONE, ONE};

    for (int kvi = 0; kvi < 16; ++kvi) {
        int kv = kvz * 1024 + kvi * 64;
        __syncthreads();
        if (wid == 0) {
#pragma unroll
            for (int p = 0; p < 8; ++p) {
                int row = p * 8 + rl;              // key
                int c = cs ^ (row & 7);
                gld16(Kn + kbase + (size_t)(kv + row) * 1024 + c * 8, Ks + p * 512);
            }
        } else {
#pragma unroll
            for (int p = 0; p < 8; ++p) {
                int row = p * 8 + rl;              // dim
                int c = cs ^ (row & 7);
                gld16(VT + vbase + (size_t)row * 2048 + kv + c * 8, Vs + p * 512);
            }
        }
        __syncthreads();   // vmcnt(0) drained -> K/V tiles ready

        // S^T = K * Q^T, one 16-key C-tile at a time; exp2+pack immediately.
#pragma unroll
        for (int i = 0; i < 4; ++i) {
            float4v sacc[4];
#pragma unroll
            for (int j = 0; j < 4; ++j) sacc[j] = zero4;
#pragma unroll
            for (int kk = 0; kk < 2; ++kk) {
                short8 kf = frag8(Ks, i * 16 + l16, kk * 4 + quad);
#pragma unroll
                for (int j = 0; j < 4; ++j)
                    sacc[j] = __builtin_amdgcn_mfma_f32_16x16x32_bf16(
                        kf, qf[j][kk], sacc[j], 0, 0, 0);
            }
            // P = 2^S; C reg-run is along keys -> pack 4 keys into b64.
#pragma unroll
            for (int j = 0; j < 4; ++j) {
                u32 e0 = __float_as_uint(__builtin_amdgcn_exp2f(sacc[j][0])) + 0x8000u;
                u32 e1 = __float_as_uint(__builtin_amdgcn_exp2f(sacc[j][1])) + 0x8000u;
                u32 e2 = __float_as_uint(__builtin_amdgcn_exp2f(sacc[j][2])) + 0x8000u;
                u32 e3 = __float_as_uint(__builtin_amdgcn_exp2f(sacc[j][3])) + 0x8000u;
                uint2 pk;
                pk.x = __builtin_amdgcn_perm(e1, e0, 0x07060302u);
                pk.y = __builtin_amdgcn_perm(e3, e2, 0x07060302u);
                *(uint2*)(&Ps[wid * 64 + j * 16 + l16][i * 16 + quad * 4]) = pk;
            }
        }

        // O += P @ V ; l += P @ ones   (Ps rows are wave-private: no barrier)
#pragma unroll
        for (int kk = 0; kk < 2; ++kk) {
            int cg = kk * 4 + quad;
            short8 pf[4];
#pragma unroll
            for (int ip = 0; ip < 4; ++ip)
                pf[ip] = *(const short8*)(
                    &Ps[wid * 64 + ip * 16 + l16][kk * 32 + quad * 8]);
#pragma unroll
            for (int jd = 0; jd < 4; ++jd) {
                short8 vf = frag8(Vs, jd * 16 + l16, cg);
#pragma unroll
                for (int ip = 0; ip < 4; ++ip)
                    oacc[ip][jd] = __builtin_amdgcn_mfma_f32_16x16x32_bf16(
                        pf[ip], vf, oacc[ip][jd], 0, 0, 0);
            }
#pragma unroll
            for (int ip = 0; ip < 4; ++ip)
                lacc[ip] = __builtin_amdgcn_mfma_f32_16x16x32_bf16(
                    pf[ip], ones, lacc[ip], 0, 0, 0);
        }
    }

    // epilogue: write bf16 numerator partials + fp32 denominator partials
    size_t obase = (size_t)kvz * 4194304;      // [kvz][4096][1024] bf16
#pragma unroll
    for (int ip = 0; ip < 4; ++ip)
#pragma unroll
        for (int r = 0; r < 4; ++r) {
            int q = q0 + ip * 16 + quad * 4 + r;
#pragma unroll
            for (int jd = 0; jd < 4; ++jd)
                Opart[obase + ((size_t)(b * 2048 + q)) * 1024 + h * 64 +
                      jd * 16 + l16] = f2b(oacc[ip][jd][r]);
        }
    if (l16 == 0) {
#pragma unroll
        for (int ip = 0; ip < 4; ++ip)
#pragma unroll
            for (int r = 0; r < 4; ++r) {
                int q = q0 + ip * 16 + quad * 4 + r;
                lpart[kvz * 65536 + (b * 2048 + q) * 16 + h] = lacc[ip][r];
            }
    }
}

// ---------------------------------------------------------------------------
// Launch
// ---------------------------------------------------------------------------
extern "C" void kernel_launch(void* const* d_in, const int* in_sizes, int n_in,
                              void* d_out, int out_size, void* d_ws, size_t ws_size,
                              hipStream_t stream) {
    const float* x  = (const float*)d_in[0];
    const float* Wq = (const float*)d_in[1];
    const float* bq = (const float*)d_in[2];
    const float* Wk = (const float*)d_in[3];
    const float* bk = (const float*)d_in[4];
    const float* Wv = (const float*)d_in[5];
    const float* bv = (const float*)d_in[6];
    const float* Wo = (const float*)d_in[7];
    const float* bo = (const float*)d_in[8];
    float* out = (float*)d_out;

    char* ws = (char*)d_ws;
    const size_t MB = 1024 * 1024;
    u16* xb  = (u16*)(ws);               //  8 MB: x bf16 [4096,1024]
    u16* wqt = (u16*)(ws + 8 * MB);      //  2 MB: Wq^T bf16
    u16* wkt = (u16*)(ws + 10 * MB);
    u16* wvt = (u16*)(ws + 12 * MB);
    u16* wot = (u16*)(ws + 14 * MB);
    u16* qb_ = (u16*)(ws + 16 * MB);     //  8 MB: Q bf16 (pre-scaled)
    u16* kb_ = (u16*)(ws + 24 * MB);     //  8 MB: K bf16
    u16* vt_ = (u16*)(ws + 32 * MB);     //  8 MB: V^T [B,H,dk,S] bf16
    u16* op_ = (u16*)(ws + 40 * MB);     // 16 MB: O partials bf16 [2][4096][1024]
    float* lp_ = (float*)(ws + 56 * MB); // 0.5 MB: l partials fp32 [2][4096][16]

    prep_kernel<<<8192, 256, 0, stream>>>(x, Wq, Wk, Wv, Wo, xb,
                                          wqt, wkt, wvt, wot);
    qkv_kernel<<<768, 256, 0, stream>>>(xb, wqt, wkt, wvt, bq, bk, bv,
                                        qb_, kb_, vt_);
    flash_kernel<<<1024, 128, 0, stream>>>(qb_, kb_, vt_, op_, lp_);
    oproj_kernel<<<256, 512, 0, stream>>>(op_, lp_, wot, bo, out);
}

// Round 11
// 192.873 us; speedup vs baseline: 1.0762x; 1.0762x over previous
//
#include <hip/hip_runtime.h>

typedef unsigned short u16;
typedef unsigned int u32;
typedef __attribute__((ext_vector_type(8))) short short8;
typedef __attribute__((ext_vector_type(4))) float float4v;

struct alignas(8) U16x4 { u16 x, y, z, w; };

// fp32 -> bf16 round-to-nearest-even
__device__ __forceinline__ u16 f2b(float f) {
    union { float f; unsigned int u; } v; v.f = f;
    unsigned int r = (v.u >> 16) & 1u;
    v.u += 0x7fffu + r;
    return (u16)(v.u >> 16);
}

__device__ __forceinline__ float b2f(u16 u) {
    union { unsigned int u; float f; } v; v.u = ((u32)u) << 16; return v.f;
}

// async global->LDS, 16B per lane; LDS dest = wave-uniform base + lane*16
__device__ __forceinline__ void gld16(const u16* g, u16* l) {
    __builtin_amdgcn_global_load_lds(
        (const __attribute__((address_space(1))) void*)g,
        (__attribute__((address_space(3))) void*)l, 16, 0, 0);
}

// read a short8 fragment from an XOR-swizzled [rows][64] u16 LDS tile.
// chunk cg (16B units within the 128B row) is stored at slot cg^(row&7).
__device__ __forceinline__ short8 frag8(const u16* base, int row, int cg) {
    return *(const short8*)(base + row * 64 + ((cg ^ (row & 7)) << 3));
}

// ---------------------------------------------------------------------------
// prep (merged): id<4096 -> x fp32->bf16 (1024 el/block);
// id>=4096 -> 32x32 transpose+cvt tile of W[z]
// ---------------------------------------------------------------------------
__global__ __launch_bounds__(256) void prep_kernel(
    const float* __restrict__ x, const float* __restrict__ W0,
    const float* __restrict__ W1, const float* __restrict__ W2,
    const float* __restrict__ W3, u16* __restrict__ xb,
    u16* __restrict__ T0, u16* __restrict__ T1,
    u16* __restrict__ T2, u16* __restrict__ T3) {
    __shared__ float tile[32][33];
    int id = blockIdx.x;
    if (id < 4096) {
        size_t i = ((size_t)id * 256 + threadIdx.x) * 4;
        float4 v = *(const float4*)(x + i);
        U16x4 o;
        o.x = f2b(v.x); o.y = f2b(v.y); o.z = f2b(v.z); o.w = f2b(v.w);
        *(U16x4*)(xb + i) = o;
        return;
    }
    int r = id - 4096;
    int z = r >> 10, tl = r & 1023;
    const float* W = (z == 0) ? W0 : (z == 1) ? W1 : (z == 2) ? W2 : W3;
    u16* T = (z == 0) ? T0 : (z == 1) ? T1 : (z == 2) ? T2 : T3;
    int t = threadIdx.x;
    int tx = t & 31, ty = t >> 5;
    int bn = (tl & 31) * 32, bk = (tl >> 5) * 32;
#pragma unroll
    for (int p = 0; p < 4; ++p) {
        int k = ty + p * 8;
        tile[k][tx] = W[(size_t)(bk + k) * 1024 + bn + tx];
    }
    __syncthreads();
#pragma unroll
    for (int p = 0; p < 4; ++p) {
        int n = ty + p * 8;
        T[(size_t)(bn + n) * 1024 + bk + tx] = f2b(tile[tx][n]);
    }
}

// ---------------------------------------------------------------------------
// GEMM core (m97 structure), 256 thr / 4 waves 2x2, 64x64 per wave.
// (used by oproj via inline below; kept for clarity)
// ---------------------------------------------------------------------------

// ---------------------------------------------------------------------------
// Z-FUSED QKV projection. grid = 256 flat (32 m x 8 n), XCD-swizzled
// (id%8 == m%8 so the 8 blocks sharing an X m-tile share an XCD).
// 512 threads = 8 waves. Staging: waves 0-1 -> As (X tile), waves 2-7 ->
// Bs[0..2] (Wq/Wk/Wv tiles) — the X A-tile is staged ONCE for all three
// GEMMs (was 3x in the unfused version; total LDS-staged bytes 393->262 MB,
// X global traffic /3, barriers /3). Compute: 2x4 wave grid, each wave
// 64m x 32n per z, acc[3][4][2] (96 VGPR).
// z=0: Q bf16 pre-scaled by 0.125*log2(e); z=1: K bf16; z=2: V^T [B,H,dk,S].
// ---------------------------------------------------------------------------
__global__ __launch_bounds__(512, 2) void qkv_kernel(
    const u16* __restrict__ X,
    const u16* __restrict__ WqT, const u16* __restrict__ WkT, const u16* __restrict__ WvT,
    const float* __restrict__ bq, const float* __restrict__ bk, const float* __restrict__ bv,
    u16* __restrict__ Qo, u16* __restrict__ Ko, u16* __restrict__ VTo) {
    __shared__ __align__(16) u16 As[128 * 64];
    __shared__ __align__(16) u16 Bs[3][128 * 64];
    int id = blockIdx.x;                       // 256 = 8 xcd * 4 mgrp * 8 n
    int m = (id & 7) | (((id >> 3) & 3) << 3); // 0..31, id%8 == m%8
    int n = id >> 5;                           // 0..7
    int t = threadIdx.x;
    int m0 = m * 128, n0 = n * 128;
    int lane = t & 63, wid = t >> 6;           // wid 0..7
    int wr = wid >> 2, wc = wid & 3;           // 2x4 wave grid; 64x32 per z
    int l16 = lane & 15, quad = lane >> 4;
    int rl = lane >> 3, cs = lane & 7;

    // staging role: tile 0 = As (from X), tiles 1..3 = Bs[z] (from W*T)
    int tileid = wid >> 1, half = wid & 1;
    const u16* gsrc = (tileid == 0) ? X : (tileid == 1) ? WqT
                     : (tileid == 2) ? WkT : WvT;
    int gbase = (tileid == 0) ? m0 : n0;
    u16* ldst = (tileid == 0) ? As : &Bs[tileid - 1][0];

    float4v acc[3][4][2];
    float4v zero4 = {0.f, 0.f, 0.f, 0.f};
#pragma unroll
    for (int z = 0; z < 3; ++z)
#pragma unroll
        for (int i = 0; i < 4; ++i)
#pragma unroll
            for (int j = 0; j < 2; ++j) acc[z][i][j] = zero4;

    for (int k0 = 0; k0 < 1024; k0 += 64) {
        __syncthreads();
#pragma unroll
        for (int p = 0; p < 8; ++p) {
            int q = half * 8 + p;            // 0..15 within the tile
            int row = q * 8 + rl;            // 0..127
            int c = cs ^ (row & 7);
            gld16(gsrc + (size_t)(gbase + row) * 1024 + k0 + c * 8, ldst + q * 512);
        }
        __syncthreads();   // vmcnt(0) drained -> all 4 tiles ready
#pragma unroll
        for (int ks = 0; ks < 64; ks += 32) {
            int cg = (ks >> 3) + quad;
            short8 af[4];
#pragma unroll
            for (int i = 0; i < 4; ++i)
                af[i] = frag8(As, wr * 64 + i * 16 + l16, cg);
#pragma unroll
            for (int z = 0; z < 3; ++z) {
                short8 bf[2];
#pragma unroll
                for (int j = 0; j < 2; ++j)
                    bf[j] = frag8(&Bs[z][0], wc * 32 + j * 16 + l16, cg);
#pragma unroll
                for (int i = 0; i < 4; ++i)
#pragma unroll
                    for (int j = 0; j < 2; ++j)
                        acc[z][i][j] = __builtin_amdgcn_mfma_f32_16x16x32_bf16(
                            af[i], bf[j], acc[z][i][j], 0, 0, 0);
            }
        }
    }

    // epilogue: Q (scaled), K natural, V^T [B,H,dk,S]
    const float QSCALE = 0.18033688011112042f;   // 0.125 * log2(e)
#pragma unroll
    for (int j = 0; j < 2; ++j) {
        int n1 = n0 + wc * 32 + j * 16 + l16;
        float bql = bq[n1], bkl = bk[n1], bvl = bv[n1];
#pragma unroll
        for (int i = 0; i < 4; ++i) {
            int mbase = m0 + wr * 64 + i * 16 + quad * 4;
#pragma unroll
            for (int r = 0; r < 4; ++r) {
                Qo[(size_t)(mbase + r) * 1024 + n1] =
                    f2b((acc[0][i][j][r] + bql) * QSCALE);
                Ko[(size_t)(mbase + r) * 1024 + n1] =
                    f2b(acc[1][i][j][r] + bkl);
            }
            // V^T: rows r are consecutive s -> 8B vector store
            int bidx = mbase >> 11, s = mbase & 2047;
            size_t base =
                ((size_t)((bidx * 16 + (n1 >> 6)) * 64 + (n1 & 63))) * 2048 + s;
            U16x4 pk;
            pk.x = f2b(acc[2][i][j][0] + bvl);
            pk.y = f2b(acc[2][i][j][1] + bvl);
            pk.z = f2b(acc[2][i][j][2] + bvl);
            pk.w = f2b(acc[2][i][j][3] + bvl);
            *(U16x4*)(VTo + base) = pk;
        }
    }
}

// ---------------------------------------------------------------------------
// Output projection: attn_out(bf16) @ Wo + bo -> fp32 [B,S,D]. grid = 256
// flat, XCD-swizzled (id%8 == m%8). 512 threads = 8 waves (2x4 grid,
// 64x32/wave). R10 errata: fusing the partial-combine into A-staging cost
// ~13 us at 1 block/CU — keep combine as its own parallel kernel.
// ---------------------------------------------------------------------------
__global__ __launch_bounds__(512) void oproj_kernel(const u16* __restrict__ X,
                                                    const u16* __restrict__ WoT,
                                                    const float* __restrict__ bias,
                                                    float* __restrict__ out) {
    __shared__ __align__(16) u16 As[128 * 64];
    __shared__ __align__(16) u16 Bs[128 * 64];
    int id = blockIdx.x;                       // 256 = 8 xcd * 4 mgrp * 8 n
    int m = (id & 7) | (((id >> 3) & 3) << 3);
    int n = id >> 5;
    int t = threadIdx.x;
    int m0 = m * 128, n0 = n * 128;
    int lane = t & 63, wid = t >> 6;           // wid 0..7
    int wr = wid >> 2, wc = wid & 3;           // 2 x 4 wave grid; 64x32 / wave
    int l16 = lane & 15, quad = lane >> 4;
    int rl = lane >> 3, cs = lane & 7;

    float4v acc[4][2];
    float4v zero4 = {0.f, 0.f, 0.f, 0.f};
#pragma unroll
    for (int i = 0; i < 4; ++i)
#pragma unroll
        for (int j = 0; j < 2; ++j) acc[i][j] = zero4;

    for (int k0 = 0; k0 < 1024; k0 += 64) {
        __syncthreads();
#pragma unroll
        for (int p = 0; p < 2; ++p) {
            int blk = wid * 2 + p;           // 0..15
            int row = blk * 8 + rl;          // 0..127
            int c = cs ^ (row & 7);
            gld16(X + (size_t)(m0 + row) * 1024 + k0 + c * 8, As + blk * 512);
            gld16(WoT + (size_t)(n0 + row) * 1024 + k0 + c * 8, Bs + blk * 512);
        }
        __syncthreads();
#pragma unroll
        for (int ks = 0; ks < 64; ks += 32) {
            int cg = (ks >> 3) + quad;
            short8 af[4], bf[2];
#pragma unroll
            for (int i = 0; i < 4; ++i) af[i] = frag8(As, wr * 64 + i * 16 + l16, cg);
#pragma unroll
            for (int j = 0; j < 2; ++j) bf[j] = frag8(Bs, wc * 32 + j * 16 + l16, cg);
#pragma unroll
            for (int i = 0; i < 4; ++i)
#pragma unroll
                for (int j = 0; j < 2; ++j)
                    acc[i][j] = __builtin_amdgcn_mfma_f32_16x16x32_bf16(
                        af[i], bf[j], acc[i][j], 0, 0, 0);
        }
    }

#pragma unroll
    for (int j = 0; j < 2; ++j) {
        int n1 = n0 + wc * 32 + j * 16 + l16;
        float bvl = bias[n1];
#pragma unroll
        for (int i = 0; i < 4; ++i) {
            int mbase = m0 + wr * 64 + i * 16 + quad * 4;
#pragma unroll
            for (int r = 0; r < 4; ++r)
                out[(size_t)(mbase + r) * 1024 + n1] = acc[i][j][r] + bvl;
        }
    }
}

// ---------------------------------------------------------------------------
// Flash attention v6 (R7, proven 51 us): 64 q/wave amortizes per-wave K/V
// fragment reads. grid = 1024 flat, XCD-swizzled (id%8 == bh%8): 8 xcd *
// 4 bhgrp * 16 qb * 2 kvz. 128 thr = 2 waves, q-tile 128 (64 q/wave),
// 64-key tiles, kv-split x2. Wave0 stages K, wave1 stages V (gld16).
// S^T = K*Q^T per 16-key C-tile, exp2 + b64 pack; PV + ones-MFMA denom.
// NOTE (R8 errata): VGPR register-prefetch of K/V spilled to scratch
// (WRITE_SIZE 20->135 MB, 2x slower). Do not re-introduce.
// ---------------------------------------------------------------------------
__global__ __launch_bounds__(128, 2) void flash_kernel(const u16* __restrict__ Q,
                                                       const u16* __restrict__ Kn,
                                                       const u16* __restrict__ VT,
                                                       u16* __restrict__ Opart,
                                                       float* __restrict__ lpart) {
    __shared__ __align__(16) u16 Ks[64 * 64];   // [key][dim] swizzled
    __shared__ __align__(16) u16 Vs[64 * 64];   // [dim][key] swizzled
    __shared__ __align__(16) u16 Ps[128][72];   // [q][key] padded (b64 w / b128 r)

    int id = blockIdx.x;                        // 1024
    int bh = (id & 7) | (((id >> 3) & 3) << 3); // id%8 == bh%8
    int rest = id >> 5;                         // 0..31
    int qb = rest & 15, kvz = rest >> 4;
    int b = bh >> 4, h = bh & 15;
    int t = threadIdx.x;
    int wid = t >> 6, lane = t & 63;
    int l16 = lane & 15, quad = lane >> 4;
    int rl = lane >> 3, cs = lane & 7;
    int q0 = qb * 128 + wid * 64;         // wave's first query
    size_t kbase = (size_t)(b * 2048) * 1024 + h * 64;
    size_t vbase = (size_t)(bh * 64) * 2048;

    // Q B-fragments (n=q, k=dim), direct from global (64B/row coalesced)
    short8 qf[4][2];
#pragma unroll
    for (int j = 0; j < 4; ++j)
#pragma unroll
        for (int kk = 0; kk < 2; ++kk)
            qf[j][kk] = *(const short8*)(
                Q + ((size_t)(b * 2048 + q0 + j * 16 + l16)) * 1024 + h * 64 +
                kk * 32 + quad * 8);

    float4v oacc[4][4], lacc[4];
    float4v zero4 = {0.f, 0.f, 0.f, 0.f};
#pragma unroll
    for (int ip = 0; ip < 4; ++ip) {
        lacc[ip] = zero4;
#pragma unroll
        for (int jd = 0; jd < 4; ++jd) oacc[ip][jd] = zero4;
    }

    const short ONE = (short)0x3F80;  // bf16 1.0
    short8 ones = {ONE, ONE, ONE, ONE, ONE, ONE, ONE, ONE};

    for (int kvi = 0; kvi < 16; ++kvi) {
        int kv = kvz * 1024 + kvi * 64;
        __syncthreads();
        if (wid == 0) {
#pragma unroll
            for (int p = 0; p < 8; ++p) {
                int row = p * 8 + rl;              // key
                int c = cs ^ (row & 7);
                gld16(Kn + kbase + (size_t)(kv + row) * 1024 + c * 8, Ks + p * 512);
            }
        } else {
#pragma unroll
            for (int p = 0; p < 8; ++p) {
                int row = p * 8 + rl;              // dim
                int c = cs ^ (row & 7);
                gld16(VT + vbase + (size_t)row * 2048 + kv + c * 8, Vs + p * 512);
            }
        }
        __syncthreads();   // vmcnt(0) drained -> K/V tiles ready

        // S^T = K * Q^T, one 16-key C-tile at a time; exp2+pack immediately.
#pragma unroll
        for (int i = 0; i < 4; ++i) {
            float4v sacc[4];
#pragma unroll
            for (int j = 0; j < 4; ++j) sacc[j] = zero4;
#pragma unroll
            for (int kk = 0; kk < 2; ++kk) {
                short8 kf = frag8(Ks, i * 16 + l16, kk * 4 + quad);
#pragma unroll
                for (int j = 0; j < 4; ++j)
                    sacc[j] = __builtin_amdgcn_mfma_f32_16x16x32_bf16(
                        kf, qf[j][kk], sacc[j], 0, 0, 0);
            }
            // P = 2^S; C reg-run is along keys -> pack 4 keys into b64.
#pragma unroll
            for (int j = 0; j < 4; ++j) {
                u32 e0 = __float_as_uint(__builtin_amdgcn_exp2f(sacc[j][0])) + 0x8000u;
                u32 e1 = __float_as_uint(__builtin_amdgcn_exp2f(sacc[j][1])) + 0x8000u;
                u32 e2 = __float_as_uint(__builtin_amdgcn_exp2f(sacc[j][2])) + 0x8000u;
                u32 e3 = __float_as_uint(__builtin_amdgcn_exp2f(sacc[j][3])) + 0x8000u;
                uint2 pk;
                pk.x = __builtin_amdgcn_perm(e1, e0, 0x07060302u);
                pk.y = __builtin_amdgcn_perm(e3, e2, 0x07060302u);
                *(uint2*)(&Ps[wid * 64 + j * 16 + l16][i * 16 + quad * 4]) = pk;
            }
        }

        // O += P @ V ; l += P @ ones   (Ps rows are wave-private: no barrier)
#pragma unroll
        for (int kk = 0; kk < 2; ++kk) {
            int cg = kk * 4 + quad;
            short8 pf[4];
#pragma unroll
            for (int ip = 0; ip < 4; ++ip)
                pf[ip] = *(const short8*)(
                    &Ps[wid * 64 + ip * 16 + l16][kk * 32 + quad * 8]);
#pragma unroll
            for (int jd = 0; jd < 4; ++jd) {
                short8 vf = frag8(Vs, jd * 16 + l16, cg);
#pragma unroll
                for (int ip = 0; ip < 4; ++ip)
                    oacc[ip][jd] = __builtin_amdgcn_mfma_f32_16x16x32_bf16(
                        pf[ip], vf, oacc[ip][jd], 0, 0, 0);
            }
#pragma unroll
            for (int ip = 0; ip < 4; ++ip)
                lacc[ip] = __builtin_amdgcn_mfma_f32_16x16x32_bf16(
                    pf[ip], ones, lacc[ip], 0, 0, 0);
        }
    }

    // epilogue: write bf16 numerator partials + fp32 denominator partials
    size_t obase = (size_t)kvz * 4194304;      // [kvz][4096][1024] bf16
#pragma unroll
    for (int ip = 0; ip < 4; ++ip)
#pragma unroll
        for (int r = 0; r < 4; ++r) {
            int q = q0 + ip * 16 + quad * 4 + r;
#pragma unroll
            for (int jd = 0; jd < 4; ++jd)
                Opart[obase + ((size_t)(b * 2048 + q)) * 1024 + h * 64 +
                      jd * 16 + l16] = f2b(oacc[ip][jd][r]);
        }
    if (l16 == 0) {
#pragma unroll
        for (int ip = 0; ip < 4; ++ip)
#pragma unroll
            for (int r = 0; r < 4; ++r) {
                int q = q0 + ip * 16 + quad * 4 + r;
                lpart[kvz * 65536 + (b * 2048 + q) * 16 + h] = lacc[ip][r];
            }
    }
}

// ---------------------------------------------------------------------------
// combine: out_bf16 = (O0+O1)/(l0+l1), 4 elems/thread. grid = 4096.
// ---------------------------------------------------------------------------
__global__ __launch_bounds__(256) void combine_kernel(const u16* __restrict__ Op,
                                                      const float* __restrict__ lp,
                                                      u16* __restrict__ out) {
    int idx = blockIdx.x * 256 + threadIdx.x;   // 0..1048575
    size_t i = (size_t)idx * 4;
    int qg = idx >> 8;                          // global row 0..4095
    int d = (idx & 255) * 4;
    int h = d >> 6;
    float l0 = lp[qg * 16 + h], l1 = lp[65536 + qg * 16 + h];
    float inv = 1.0f / (l0 + l1);
    U16x4 o0 = *(const U16x4*)(Op + i);
    U16x4 o1 = *(const U16x4*)(Op + 4194304 + i);
    U16x4 o;
    o.x = f2b((b2f(o0.x) + b2f(o1.x)) * inv);
    o.y = f2b((b2f(o0.y) + b2f(o1.y)) * inv);
    o.z = f2b((b2f(o0.z) + b2f(o1.z)) * inv);
    o.w = f2b((b2f(o0.w) + b2f(o1.w)) * inv);
    *(U16x4*)(out + i) = o;
}

// ---------------------------------------------------------------------------
// Launch
// ---------------------------------------------------------------------------
extern "C" void kernel_launch(void* const* d_in, const int* in_sizes, int n_in,
                              void* d_out, int out_size, void* d_ws, size_t ws_size,
                              hipStream_t stream) {
    const float* x  = (const float*)d_in[0];
    const float* Wq = (const float*)d_in[1];
    const float* bq = (const float*)d_in[2];
    const float* Wk = (const float*)d_in[3];
    const float* bk = (const float*)d_in[4];
    const float* Wv = (const float*)d_in[5];
    const float* bv = (const float*)d_in[6];
    const float* Wo = (const float*)d_in[7];
    const float* bo = (const float*)d_in[8];
    float* out = (float*)d_out;

    char* ws = (char*)d_ws;
    const size_t MB = 1024 * 1024;
    u16* xb  = (u16*)(ws);               //  8 MB: x bf16 [4096,1024]
    u16* wqt = (u16*)(ws + 8 * MB);      //  2 MB: Wq^T bf16
    u16* wkt = (u16*)(ws + 10 * MB);
    u16* wvt = (u16*)(ws + 12 * MB);
    u16* wot = (u16*)(ws + 14 * MB);
    u16* qb_ = (u16*)(ws + 16 * MB);     //  8 MB: Q bf16 (pre-scaled)
    u16* kb_ = (u16*)(ws + 24 * MB);     //  8 MB: K bf16
    u16* vt_ = (u16*)(ws + 32 * MB);     //  8 MB: V^T [B,H,dk,S] bf16
    u16* ab_ = (u16*)(ws + 40 * MB);     //  8 MB: attn out bf16
    u16* op_ = (u16*)(ws + 48 * MB);     // 16 MB: O partials bf16 [2][4096][1024]
    float* lp_ = (float*)(ws + 64 * MB); // 0.5 MB: l partials fp32 [2][4096][16]

    prep_kernel<<<8192, 256, 0, stream>>>(x, Wq, Wk, Wv, Wo, xb,
                                          wqt, wkt, wvt, wot);
    qkv_kernel<<<256, 512, 0, stream>>>(xb, wqt, wkt, wvt, bq, bk, bv,
                                        qb_, kb_, vt_);
    flash_kernel<<<1024, 128, 0, stream>>>(qb_, kb_, vt_, op_, lp_);
    combine_kernel<<<4096, 256, 0, stream>>>(op_, lp_, ab_);
    oproj_kernel<<<256, 512, 0, stream>>>(ab_, wot, bo, out);
}

// Round 12
// 192.043 us; speedup vs baseline: 1.0808x; 1.0043x over previous
//
#include <hip/hip_runtime.h>

typedef unsigned short u16;
typedef unsigned int u32;
typedef __attribute__((ext_vector_type(8))) short short8;
typedef __attribute__((ext_vector_type(4))) float float4v;

struct alignas(8) U16x4 { u16 x, y, z, w; };

// fp32 -> bf16 round-to-nearest-even
__device__ __forceinline__ u16 f2b(float f) {
    union { float f; unsigned int u; } v; v.f = f;
    unsigned int r = (v.u >> 16) & 1u;
    v.u += 0x7fffu + r;
    return (u16)(v.u >> 16);
}

__device__ __forceinline__ float b2f(u16 u) {
    union { unsigned int u; float f; } v; v.u = ((u32)u) << 16; return v.f;
}

// async global->LDS, 16B per lane; LDS dest = wave-uniform base + lane*16
__device__ __forceinline__ void gld16(const u16* g, u16* l) {
    __builtin_amdgcn_global_load_lds(
        (const __attribute__((address_space(1))) void*)g,
        (__attribute__((address_space(3))) void*)l, 16, 0, 0);
}

// read a short8 fragment from an XOR-swizzled [rows][64] u16 LDS tile.
// chunk cg (16B units within the 128B row) is stored at slot cg^(row&7).
__device__ __forceinline__ short8 frag8(const u16* base, int row, int cg) {
    return *(const short8*)(base + row * 64 + ((cg ^ (row & 7)) << 3));
}

// ---------------------------------------------------------------------------
// prep (merged): id<4096 -> x fp32->bf16 (1024 el/block);
// id>=4096 -> 32x32 transpose+cvt tile of W[z]
// ---------------------------------------------------------------------------
__global__ __launch_bounds__(256) void prep_kernel(
    const float* __restrict__ x, const float* __restrict__ W0,
    const float* __restrict__ W1, const float* __restrict__ W2,
    const float* __restrict__ W3, u16* __restrict__ xb,
    u16* __restrict__ T0, u16* __restrict__ T1,
    u16* __restrict__ T2, u16* __restrict__ T3) {
    __shared__ float tile[32][33];
    int id = blockIdx.x;
    if (id < 4096) {
        size_t i = ((size_t)id * 256 + threadIdx.x) * 4;
        float4 v = *(const float4*)(x + i);
        U16x4 o;
        o.x = f2b(v.x); o.y = f2b(v.y); o.z = f2b(v.z); o.w = f2b(v.w);
        *(U16x4*)(xb + i) = o;
        return;
    }
    int r = id - 4096;
    int z = r >> 10, tl = r & 1023;
    const float* W = (z == 0) ? W0 : (z == 1) ? W1 : (z == 2) ? W2 : W3;
    u16* T = (z == 0) ? T0 : (z == 1) ? T1 : (z == 2) ? T2 : T3;
    int t = threadIdx.x;
    int tx = t & 31, ty = t >> 5;
    int bn = (tl & 31) * 32, bk = (tl >> 5) * 32;
#pragma unroll
    for (int p = 0; p < 4; ++p) {
        int k = ty + p * 8;
        tile[k][tx] = W[(size_t)(bk + k) * 1024 + bn + tx];
    }
    __syncthreads();
#pragma unroll
    for (int p = 0; p < 4; ++p) {
        int n = ty + p * 8;
        T[(size_t)(bn + n) * 1024 + bk + tx] = f2b(tile[tx][n]);
    }
}

// ---------------------------------------------------------------------------
// Z-FUSED QKV projection (R11, proven). grid = 256 flat (32 m x 8 n),
// XCD-swizzled (id%8 == m%8). 512 threads = 8 waves. Staging: waves 0-1 ->
// As (X tile), waves 2-7 -> Bs[0..2]; X A-tile staged ONCE for all three
// GEMMs. Compute: 2x4 wave grid, each wave 64m x 32n per z.
// z=0: Q bf16 pre-scaled by 0.125*log2(e); z=1: K bf16; z=2: V^T [B,H,dk,S].
// ---------------------------------------------------------------------------
__global__ __launch_bounds__(512, 2) void qkv_kernel(
    const u16* __restrict__ X,
    const u16* __restrict__ WqT, const u16* __restrict__ WkT, const u16* __restrict__ WvT,
    const float* __restrict__ bq, const float* __restrict__ bk, const float* __restrict__ bv,
    u16* __restrict__ Qo, u16* __restrict__ Ko, u16* __restrict__ VTo) {
    __shared__ __align__(16) u16 As[128 * 64];
    __shared__ __align__(16) u16 Bs[3][128 * 64];
    int id = blockIdx.x;                       // 256 = 8 xcd * 4 mgrp * 8 n
    int m = (id & 7) | (((id >> 3) & 3) << 3); // 0..31, id%8 == m%8
    int n = id >> 5;                           // 0..7
    int t = threadIdx.x;
    int m0 = m * 128, n0 = n * 128;
    int lane = t & 63, wid = t >> 6;           // wid 0..7
    int wr = wid >> 2, wc = wid & 3;           // 2x4 wave grid; 64x32 per z
    int l16 = lane & 15, quad = lane >> 4;
    int rl = lane >> 3, cs = lane & 7;

    // staging role: tile 0 = As (from X), tiles 1..3 = Bs[z] (from W*T)
    int tileid = wid >> 1, half = wid & 1;
    const u16* gsrc = (tileid == 0) ? X : (tileid == 1) ? WqT
                     : (tileid == 2) ? WkT : WvT;
    int gbase = (tileid == 0) ? m0 : n0;
    u16* ldst = (tileid == 0) ? As : &Bs[tileid - 1][0];

    float4v acc[3][4][2];
    float4v zero4 = {0.f, 0.f, 0.f, 0.f};
#pragma unroll
    for (int z = 0; z < 3; ++z)
#pragma unroll
        for (int i = 0; i < 4; ++i)
#pragma unroll
            for (int j = 0; j < 2; ++j) acc[z][i][j] = zero4;

    for (int k0 = 0; k0 < 1024; k0 += 64) {
        __syncthreads();
#pragma unroll
        for (int p = 0; p < 8; ++p) {
            int q = half * 8 + p;            // 0..15 within the tile
            int row = q * 8 + rl;            // 0..127
            int c = cs ^ (row & 7);
            gld16(gsrc + (size_t)(gbase + row) * 1024 + k0 + c * 8, ldst + q * 512);
        }
        __syncthreads();   // vmcnt(0) drained -> all 4 tiles ready
#pragma unroll
        for (int ks = 0; ks < 64; ks += 32) {
            int cg = (ks >> 3) + quad;
            short8 af[4];
#pragma unroll
            for (int i = 0; i < 4; ++i)
                af[i] = frag8(As, wr * 64 + i * 16 + l16, cg);
#pragma unroll
            for (int z = 0; z < 3; ++z) {
                short8 bf[2];
#pragma unroll
                for (int j = 0; j < 2; ++j)
                    bf[j] = frag8(&Bs[z][0], wc * 32 + j * 16 + l16, cg);
#pragma unroll
                for (int i = 0; i < 4; ++i)
#pragma unroll
                    for (int j = 0; j < 2; ++j)
                        acc[z][i][j] = __builtin_amdgcn_mfma_f32_16x16x32_bf16(
                            af[i], bf[j], acc[z][i][j], 0, 0, 0);
            }
        }
    }

    // epilogue: Q (scaled), K natural, V^T [B,H,dk,S]
    const float QSCALE = 0.18033688011112042f;   // 0.125 * log2(e)
#pragma unroll
    for (int j = 0; j < 2; ++j) {
        int n1 = n0 + wc * 32 + j * 16 + l16;
        float bql = bq[n1], bkl = bk[n1], bvl = bv[n1];
#pragma unroll
        for (int i = 0; i < 4; ++i) {
            int mbase = m0 + wr * 64 + i * 16 + quad * 4;
#pragma unroll
            for (int r = 0; r < 4; ++r) {
                Qo[(size_t)(mbase + r) * 1024 + n1] =
                    f2b((acc[0][i][j][r] + bql) * QSCALE);
                Ko[(size_t)(mbase + r) * 1024 + n1] =
                    f2b(acc[1][i][j][r] + bkl);
            }
            // V^T: rows r are consecutive s -> 8B vector store
            int bidx = mbase >> 11, s = mbase & 2047;
            size_t base =
                ((size_t)((bidx * 16 + (n1 >> 6)) * 64 + (n1 & 63))) * 2048 + s;
            U16x4 pk;
            pk.x = f2b(acc[2][i][j][0] + bvl);
            pk.y = f2b(acc[2][i][j][1] + bvl);
            pk.z = f2b(acc[2][i][j][2] + bvl);
            pk.w = f2b(acc[2][i][j][3] + bvl);
            *(U16x4*)(VTo + base) = pk;
        }
    }
}

// ---------------------------------------------------------------------------
// Output projection: attn_out(bf16) @ Wo + bo -> fp32 [B,S,D].
// grid = 512 flat (64 m-tiles of 64 rows x 8 n), XCD-swizzled (id%8==m%8)
// -> 2 blocks/CU (was 1 at grid 256). 256 thr = 4 waves, each 64m x 32n.
// LDS 24 KB.
// ---------------------------------------------------------------------------
__global__ __launch_bounds__(256) void oproj_kernel(const u16* __restrict__ X,
                                                    const u16* __restrict__ WoT,
                                                    const float* __restrict__ bias,
                                                    float* __restrict__ out) {
    __shared__ __align__(16) u16 As[64 * 64];
    __shared__ __align__(16) u16 Bs[128 * 64];
    int id = blockIdx.x;                       // 512 = 8 xcd * 8 mgrp * 8 n
    int m = (id & 7) | (((id >> 3) & 7) << 3); // 0..63, id%8 == m%8
    int n = id >> 6;                           // 0..7
    int t = threadIdx.x;
    int m0 = m * 64, n0 = n * 128;
    int lane = t & 63, wid = t >> 6;           // wid 0..3
    int l16 = lane & 15, quad = lane >> 4;
    int rl = lane >> 3, cs = lane & 7;

    float4v acc[4][2];
    float4v zero4 = {0.f, 0.f, 0.f, 0.f};
#pragma unroll
    for (int i = 0; i < 4; ++i)
#pragma unroll
        for (int j = 0; j < 2; ++j) acc[i][j] = zero4;

    for (int k0 = 0; k0 < 1024; k0 += 64) {
        __syncthreads();
        // As: 64 rows = 8 groups, 2 per wave
#pragma unroll
        for (int p = 0; p < 2; ++p) {
            int blk = wid * 2 + p;           // 0..7
            int row = blk * 8 + rl;          // 0..63
            int c = cs ^ (row & 7);
            gld16(X + (size_t)(m0 + row) * 1024 + k0 + c * 8, As + blk * 512);
        }
        // Bs: 128 rows = 16 groups, 4 per wave
#pragma unroll
        for (int p = 0; p < 4; ++p) {
            int blk = wid * 4 + p;           // 0..15
            int row = blk * 8 + rl;          // 0..127
            int c = cs ^ (row & 7);
            gld16(WoT + (size_t)(n0 + row) * 1024 + k0 + c * 8, Bs + blk * 512);
        }
        __syncthreads();
#pragma unroll
        for (int ks = 0; ks < 64; ks += 32) {
            int cg = (ks >> 3) + quad;
            short8 af[4], bf[2];
#pragma unroll
            for (int i = 0; i < 4; ++i) af[i] = frag8(As, i * 16 + l16, cg);
#pragma unroll
            for (int j = 0; j < 2; ++j) bf[j] = frag8(Bs, wid * 32 + j * 16 + l16, cg);
#pragma unroll
            for (int i = 0; i < 4; ++i)
#pragma unroll
                for (int j = 0; j < 2; ++j)
                    acc[i][j] = __builtin_amdgcn_mfma_f32_16x16x32_bf16(
                        af[i], bf[j], acc[i][j], 0, 0, 0);
        }
    }

#pragma unroll
    for (int j = 0; j < 2; ++j) {
        int n1 = n0 + wid * 32 + j * 16 + l16;
        float bvl = bias[n1];
#pragma unroll
        for (int i = 0; i < 4; ++i) {
            int mbase = m0 + i * 16 + quad * 4;
#pragma unroll
            for (int r = 0; r < 4; ++r)
                out[(size_t)(mbase + r) * 1024 + n1] = acc[i][j][r] + bvl;
        }
    }
}

// ---------------------------------------------------------------------------
// Flash attention v8: R7 structure + VALU denominator (no ones-MFMA).
// grid = 1024 flat, XCD-swizzled (id%8 == bh%8). 128 thr = 2 waves,
// q-tile 128 (64 q/wave), 64-key tiles, kv-split x2. Wave0 stages K,
// wave1 stages V (gld16). S^T = K*Q^T per 16-key C-tile; exp2 values are
// summed in fp32 VALU registers (lreg[j], q = j*16+l16) BEFORE the bf16
// pack -- removes 8 of 72 MFMAs/iter; one cross-quad shuffle reduction at
// the end. NOTE (R8 errata): VGPR register-prefetch of K/V spills. No.
// ---------------------------------------------------------------------------
__global__ __launch_bounds__(128, 2) void flash_kernel(const u16* __restrict__ Q,
                                                       const u16* __restrict__ Kn,
                                                       const u16* __restrict__ VT,
                                                       u16* __restrict__ Opart,
                                                       float* __restrict__ lpart) {
    __shared__ __align__(16) u16 Ks[64 * 64];   // [key][dim] swizzled
    __shared__ __align__(16) u16 Vs[64 * 64];   // [dim][key] swizzled
    __shared__ __align__(16) u16 Ps[128][72];   // [q][key] padded (b64 w / b128 r)

    int id = blockIdx.x;                        // 1024
    int bh = (id & 7) | (((id >> 3) & 3) << 3); // id%8 == bh%8
    int rest = id >> 5;                         // 0..31
    int qb = rest & 15, kvz = rest >> 4;
    int b = bh >> 4, h = bh & 15;
    int t = threadIdx.x;
    int wid = t >> 6, lane = t & 63;
    int l16 = lane & 15, quad = lane >> 4;
    int rl = lane >> 3, cs = lane & 7;
    int q0 = qb * 128 + wid * 64;         // wave's first query
    size_t kbase = (size_t)(b * 2048) * 1024 + h * 64;
    size_t vbase = (size_t)(bh * 64) * 2048;

    // Q B-fragments (n=q, k=dim), direct from global (64B/row coalesced)
    short8 qf[4][2];
#pragma unroll
    for (int j = 0; j < 4; ++j)
#pragma unroll
        for (int kk = 0; kk < 2; ++kk)
            qf[j][kk] = *(const short8*)(
                Q + ((size_t)(b * 2048 + q0 + j * 16 + l16)) * 1024 + h * 64 +
                kk * 32 + quad * 8);

    float4v oacc[4][4];
    float lreg[4];
    float4v zero4 = {0.f, 0.f, 0.f, 0.f};
#pragma unroll
    for (int ip = 0; ip < 4; ++ip) {
        lreg[ip] = 0.f;
#pragma unroll
        for (int jd = 0; jd < 4; ++jd) oacc[ip][jd] = zero4;
    }

    for (int kvi = 0; kvi < 16; ++kvi) {
        int kv = kvz * 1024 + kvi * 64;
        __syncthreads();
        if (wid == 0) {
#pragma unroll
            for (int p = 0; p < 8; ++p) {
                int row = p * 8 + rl;              // key
                int c = cs ^ (row & 7);
                gld16(Kn + kbase + (size_t)(kv + row) * 1024 + c * 8, Ks + p * 512);
            }
        } else {
#pragma unroll
            for (int p = 0; p < 8; ++p) {
                int row = p * 8 + rl;              // dim
                int c = cs ^ (row & 7);
                gld16(VT + vbase + (size_t)row * 2048 + kv + c * 8, Vs + p * 512);
            }
        }
        __syncthreads();   // vmcnt(0) drained -> K/V tiles ready

        // S^T = K * Q^T, one 16-key C-tile at a time; exp2+pack immediately.
#pragma unroll
        for (int i = 0; i < 4; ++i) {
            float4v sacc[4];
#pragma unroll
            for (int j = 0; j < 4; ++j) sacc[j] = zero4;
#pragma unroll
            for (int kk = 0; kk < 2; ++kk) {
                short8 kf = frag8(Ks, i * 16 + l16, kk * 4 + quad);
#pragma unroll
                for (int j = 0; j < 4; ++j)
                    sacc[j] = __builtin_amdgcn_mfma_f32_16x16x32_bf16(
                        kf, qf[j][kk], sacc[j], 0, 0, 0);
            }
            // P = 2^S; accumulate fp32 denominator, pack bf16 numerator.
#pragma unroll
            for (int j = 0; j < 4; ++j) {
                float e0f = __builtin_amdgcn_exp2f(sacc[j][0]);
                float e1f = __builtin_amdgcn_exp2f(sacc[j][1]);
                float e2f = __builtin_amdgcn_exp2f(sacc[j][2]);
                float e3f = __builtin_amdgcn_exp2f(sacc[j][3]);
                lreg[j] += (e0f + e1f) + (e2f + e3f);
                u32 e0 = __float_as_uint(e0f) + 0x8000u;
                u32 e1 = __float_as_uint(e1f) + 0x8000u;
                u32 e2 = __float_as_uint(e2f) + 0x8000u;
                u32 e3 = __float_as_uint(e3f) + 0x8000u;
                uint2 pk;
                pk.x = __builtin_amdgcn_perm(e1, e0, 0x07060302u);
                pk.y = __builtin_amdgcn_perm(e3, e2, 0x07060302u);
                *(uint2*)(&Ps[wid * 64 + j * 16 + l16][i * 16 + quad * 4]) = pk;
            }
        }

        // O += P @ V   (Ps rows are wave-private: no barrier)
#pragma unroll
        for (int kk = 0; kk < 2; ++kk) {
            int cg = kk * 4 + quad;
            short8 pf[4];
#pragma unroll
            for (int ip = 0; ip < 4; ++ip)
                pf[ip] = *(const short8*)(
                    &Ps[wid * 64 + ip * 16 + l16][kk * 32 + quad * 8]);
#pragma unroll
            for (int jd = 0; jd < 4; ++jd) {
                short8 vf = frag8(Vs, jd * 16 + l16, cg);
#pragma unroll
                for (int ip = 0; ip < 4; ++ip)
                    oacc[ip][jd] = __builtin_amdgcn_mfma_f32_16x16x32_bf16(
                        pf[ip], vf, oacc[ip][jd], 0, 0, 0);
            }
        }
    }

    // reduce denominator across quads (lanes same l16): keys quad*4+r
    // partitions -> xor-16 and xor-32 shuffles complete the key sum.
#pragma unroll
    for (int j = 0; j < 4; ++j) {
        lreg[j] += __shfl_xor(lreg[j], 16);
        lreg[j] += __shfl_xor(lreg[j], 32);
    }

    // epilogue: write bf16 numerator partials + fp32 denominator partials
    size_t obase = (size_t)kvz * 4194304;      // [kvz][4096][1024] bf16
#pragma unroll
    for (int ip = 0; ip < 4; ++ip)
#pragma unroll
        for (int r = 0; r < 4; ++r) {
            int q = q0 + ip * 16 + quad * 4 + r;
#pragma unroll
            for (int jd = 0; jd < 4; ++jd)
                Opart[obase + ((size_t)(b * 2048 + q)) * 1024 + h * 64 +
                      jd * 16 + l16] = f2b(oacc[ip][jd][r]);
        }
    if (quad == 0) {
#pragma unroll
        for (int j = 0; j < 4; ++j) {
            int q = q0 + j * 16 + l16;
            lpart[kvz * 65536 + (b * 2048 + q) * 16 + h] = lreg[j];
        }
    }
}

// ---------------------------------------------------------------------------
// combine: out_bf16 = (O0+O1)/(l0+l1), 4 elems/thread. grid = 4096.
// ---------------------------------------------------------------------------
__global__ __launch_bounds__(256) void combine_kernel(const u16* __restrict__ Op,
                                                      const float* __restrict__ lp,
                                                      u16* __restrict__ out) {
    int idx = blockIdx.x * 256 + threadIdx.x;   // 0..1048575
    size_t i = (size_t)idx * 4;
    int qg = idx >> 8;                          // global row 0..4095
    int d = (idx & 255) * 4;
    int h = d >> 6;
    float l0 = lp[qg * 16 + h], l1 = lp[65536 + qg * 16 + h];
    float inv = 1.0f / (l0 + l1);
    U16x4 o0 = *(const U16x4*)(Op + i);
    U16x4 o1 = *(const U16x4*)(Op + 4194304 + i);
    U16x4 o;
    o.x = f2b((b2f(o0.x) + b2f(o1.x)) * inv);
    o.y = f2b((b2f(o0.y) + b2f(o1.y)) * inv);
    o.z = f2b((b2f(o0.z) + b2f(o1.z)) * inv);
    o.w = f2b((b2f(o0.w) + b2f(o1.w)) * inv);
    *(U16x4*)(out + i) = o;
}

// ---------------------------------------------------------------------------
// Launch
// ---------------------------------------------------------------------------
extern "C" void kernel_launch(void* const* d_in, const int* in_sizes, int n_in,
                              void* d_out, int out_size, void* d_ws, size_t ws_size,
                              hipStream_t stream) {
    const float* x  = (const float*)d_in[0];
    const float* Wq = (const float*)d_in[1];
    const float* bq = (const float*)d_in[2];
    const float* Wk = (const float*)d_in[3];
    const float* bk = (const float*)d_in[4];
    const float* Wv = (const float*)d_in[5];
    const float* bv = (const float*)d_in[6];
    const float* Wo = (const float*)d_in[7];
    const float* bo = (const float*)d_in[8];
    float* out = (float*)d_out;

    char* ws = (char*)d_ws;
    const size_t MB = 1024 * 1024;
    u16* xb  = (u16*)(ws);               //  8 MB: x bf16 [4096,1024]
    u16* wqt = (u16*)(ws + 8 * MB);      //  2 MB: Wq^T bf16
    u16* wkt = (u16*)(ws + 10 * MB);
    u16* wvt = (u16*)(ws + 12 * MB);
    u16* wot = (u16*)(ws + 14 * MB);
    u16* qb_ = (u16*)(ws + 16 * MB);     //  8 MB: Q bf16 (pre-scaled)
    u16* kb_ = (u16*)(ws + 24 * MB);     //  8 MB: K bf16
    u16* vt_ = (u16*)(ws + 32 * MB);     //  8 MB: V^T [B,H,dk,S] bf16
    u16* ab_ = (u16*)(ws + 40 * MB);     //  8 MB: attn out bf16
    u16* op_ = (u16*)(ws + 48 * MB);     // 16 MB: O partials bf16 [2][4096][1024]
    float* lp_ = (float*)(ws + 64 * MB); // 0.5 MB: l partials fp32 [2][4096][16]

    prep_kernel<<<8192, 256, 0, stream>>>(x, Wq, Wk, Wv, Wo, xb,
                                          wqt, wkt, wvt, wot);
    qkv_kernel<<<256, 512, 0, stream>>>(xb, wqt, wkt, wvt, bq, bk, bv,
                                        qb_, kb_, vt_);
    flash_kernel<<<1024, 128, 0, stream>>>(qb_, kb_, vt_, op_, lp_);
    combine_kernel<<<4096, 256, 0, stream>>>(op_, lp_, ab_);
    oproj_kernel<<<512, 256, 0, stream>>>(ab_, wot, bo, out);
}